// Round 3
// baseline (333.091 us; speedup 1.0000x reference)
//
#include <hip/hip_runtime.h>

// emb lookup -> RNN tanh(xp_t + h @ W_hh^T) over S=128 -> 5-class head.
// B=4096, S=128, D=256, VOCAB=50000. Floats f32, x int32, out f32.
//
// Phase 0: P[v] = bf16(emb[v] @ W_ih^T + b_ih + b_hh) — project the 50k TABLE.
//   Exact round-0 structure (best measured): LDS-staged, coalesced 16B loads /
//   uint4 stores, grid 256. R1 (direct-load) and R2 (grid 512 + lgkm barriers)
//   both regressed it — reverted.
// Phase 1 (R9): TLP fix. rocprof across R0-R2 shows rnn is latency-exposed,
//   not pipe-bound: step 2520-2680cy vs ~500cy ideal chain, MfmaUtil 19-21%,
//   VALUBusy 41-43%, and all waves stall in lockstep on ONE block-wide barrier
//   (4-wave/1-per-SIMD R2 regressed vs 8-wave R1: occupancy, not LDS traffic,
//   is binding). Fix: TWO independent barrier domains per CU — grid 512 x
//   8 rows/block, 8 waves x 32 cols (round-0 wave structure, VGPR~100 ->
//   4 waves/SIMD, LDS 2x30KB fits). Block B's compute fills block A's latency
//   shadows. Cost: 16-row MFMA tiles half-valid (2x MFMA/VALU issue per CU,
//   affordable at 19%/41% busy). Rows 8-15 of h stay zero; gathers/tanh/writes
//   gated to quad<2; prologue gather gated (avoids OOB x reads).
//   Barriers lgkm-only (T4): gathers stay in flight across barriers.

typedef __attribute__((ext_vector_type(8))) short bf16x8;   // 8 bf16 = 4 VGPRs
typedef __attribute__((ext_vector_type(4))) float f32x4;    // MFMA 16x16 accumulator

#define VOCAB 50000
#define NBLK_EMB 256
#define LDS_STRIDE 264   // emb kernel staging only

__device__ __align__(256) unsigned short g_P[VOCAB * 256];  // 25.6 MB projected table

static __device__ __forceinline__ float bf2f(unsigned short u) {
    union { unsigned int i; float f; } v; v.i = ((unsigned int)u) << 16; return v.f;
}
static __device__ __forceinline__ float bfbits2f(unsigned int zext_u16) {
    union { unsigned int i; float f; } v; v.i = zext_u16 << 16; return v.f;
}
static __device__ __forceinline__ unsigned short f2bf_rne(float f) {
    union { float f; unsigned int i; } v; v.f = f;
    unsigned int r = v.i + 0x7FFFu + ((v.i >> 16) & 1u);
    return (unsigned short)(r >> 16);
}
static __device__ __forceinline__ unsigned short f2bf_fast(float f) {   // round-half-up
    union { float f; unsigned int i; } v; v.f = f;
    return (unsigned short)((v.i + 0x8000u) >> 16);
}
static __device__ __forceinline__ bf16x8 cvt8(float4 a, float4 b) {
    bf16x8 r;
    r[0] = (short)f2bf_rne(a.x); r[1] = (short)f2bf_rne(a.y);
    r[2] = (short)f2bf_rne(a.z); r[3] = (short)f2bf_rne(a.w);
    r[4] = (short)f2bf_rne(b.x); r[5] = (short)f2bf_rne(b.y);
    r[6] = (short)f2bf_rne(b.z); r[7] = (short)f2bf_rne(b.w);
    return r;
}
static __device__ __forceinline__ bf16x8 load8_bf(const float* __restrict__ p) {
    return cvt8(((const float4*)p)[0], ((const float4*)p)[1]);
}
// tanh(x) = 1 - 2/(e^{2x}+1); med3 clamp keeps exp finite
static __device__ __forceinline__ float fast_tanh(float x) {
    x = __builtin_amdgcn_fmed3f(x, -8.f, 8.f);
    float e = __expf(2.f * x);
    return __builtin_fmaf(-2.f, __builtin_amdgcn_rcpf(e + 1.f), 1.f);
}
// Workgroup barrier that does NOT drain vmcnt: only LDS ops must be visible.
// All cross-wave hazards in rnn are LDS<->LDS; in-flight global gathers keep
// counted vmcnt waits at their consumption sites (2 steps later).
static __device__ __forceinline__ void barrier_lds_only() {
    asm volatile("s_waitcnt lgkmcnt(0)\n\ts_barrier" ::: "memory");
}

// ---------------- Phase 0: P = bf16(emb @ W_ih^T + (b_ih + b_hh)) ----------------
__global__ __launch_bounds__(256)
void emb_proj_kernel(const float* __restrict__ emb,
                     const float* __restrict__ W_ih,
                     const float* __restrict__ b_ih,
                     const float* __restrict__ b_hh)
{
    __shared__ __align__(16) unsigned short tin [16 * LDS_STRIDE];
    __shared__ __align__(16) unsigned short tout[16 * LDS_STRIDE];
    const int tid  = threadIdx.x;
    const int lane = tid & 63;
    const int wid  = tid >> 6;
    const int n0   = wid * 64;
    const int row  = tid >> 4, seg = tid & 15;

    bf16x8 wf[4][8];
    float  bias[4];
    #pragma unroll
    for (int nt = 0; nt < 4; ++nt) {
        int n = n0 + nt * 16 + (lane & 15);
        bias[nt] = b_ih[n] + b_hh[n];
        #pragma unroll
        for (int kt = 0; kt < 8; ++kt)
            wf[nt][kt] = load8_bf(W_ih + n * 256 + (lane >> 4) * 8 + kt * 32);
    }

    int tile = blockIdx.x;
    float4 a0, a1, a2, a3;
    {
        const float4* s = (const float4*)(emb + ((size_t)tile * 16 + row) * 256 + seg * 16);
        a0 = s[0]; a1 = s[1]; a2 = s[2]; a3 = s[3];
    }

    for (; tile < 3125; tile += NBLK_EMB) {
        *(bf16x8*)(&tin[row * LDS_STRIDE + seg * 16])     = cvt8(a0, a1);
        *(bf16x8*)(&tin[row * LDS_STRIDE + seg * 16 + 8]) = cvt8(a2, a3);
        int tn = tile + NBLK_EMB;
        if (tn < 3125) {
            const float4* s = (const float4*)(emb + ((size_t)tn * 16 + row) * 256 + seg * 16);
            a0 = s[0]; a1 = s[1]; a2 = s[2]; a3 = s[3];
        }
        __syncthreads();   // B1: tin visible

        f32x4 acc[4];
        #pragma unroll
        for (int nt = 0; nt < 4; ++nt) acc[nt] = (f32x4){0.f, 0.f, 0.f, 0.f};
        #pragma unroll
        for (int kt = 0; kt < 8; ++kt) {
            bf16x8 a = *(bf16x8*)(&tin[(lane & 15) * LDS_STRIDE + (lane >> 4) * 8 + kt * 32]);
            #pragma unroll
            for (int nt = 0; nt < 4; ++nt)
                acc[nt] = __builtin_amdgcn_mfma_f32_16x16x32_bf16(a, wf[nt][kt], acc[nt], 0, 0, 0);
        }
        #pragma unroll
        for (int nt = 0; nt < 4; ++nt) {
            int n = n0 + nt * 16 + (lane & 15);
            #pragma unroll
            for (int r = 0; r < 4; ++r)
                tout[((lane >> 4) * 4 + r) * LDS_STRIDE + n] = f2bf_rne(acc[nt][r] + bias[nt]);
        }
        __syncthreads();   // B2: tout complete, tin reads complete
        {
            uint4 o0 = *(uint4*)(&tout[row * LDS_STRIDE + seg * 16]);
            uint4 o1 = *(uint4*)(&tout[row * LDS_STRIDE + seg * 16 + 8]);
            uint4* dst = (uint4*)(g_P + ((size_t)tile * 16 + row) * 256 + seg * 16);
            dst[0] = o0; dst[1] = o1;
        }
    }
}

// ---------------- Phase 1: recurrence + classifier ----------------
// 512 blocks x 8 rows. h LDS layout (per 8KB buffer, 16 row-slots, rows 8-15
// permanently zero): element (row m, col c) at byte
//   m*512 + (((c>>3) ^ m) << 4) + (c&7)*2      (granule-XOR swizzle, conflict-free)
__global__ __launch_bounds__(512, 2)
void rnn_kernel(const int* __restrict__ x,
                const float* __restrict__ W_hh,
                const float* __restrict__ W_cls,
                const float* __restrict__ b_cls,
                float* __restrict__ out)
{
    __shared__ __align__(16) unsigned short h_lds[2][16 * 256];  // 2 x 8 KB
    __shared__ __align__(16) int tok_t[128 * 8];                 // [t][row]
    __shared__ __align__(16) float wcls_lds[5 * 256];
    __shared__ float bcls_lds[5];

    const int tid  = threadIdx.x;
    const int lane = tid & 63;
    const int wid  = tid >> 6;          // 8 waves
    const int b0   = blockIdx.x * 8;    // 8 batch rows per block
    const int n0   = wid * 32;          // wave's 32-col slice
    const int l15  = lane & 15;
    const int quad = lane >> 4;
    const bool rowv = (quad < 2);       // lanes whose output rows (quad*4+r) are valid

    // W_hh -> bf16 B-fragments, VGPR-resident
    bf16x8 wf[2][8];
    #pragma unroll
    for (int nt = 0; nt < 2; ++nt) {
        int n = n0 + nt * 16 + l15;
        #pragma unroll
        for (int kt = 0; kt < 8; ++kt)
            wf[nt][kt] = load8_bf(W_hh + n * 256 + quad * 8 + kt * 32);
    }

    // stage tokens transposed: tok_t[t*8 + row]  (256 threads x int4 = 1024 ints)
    if (tid < 256) {
        int row = tid & 7, tq = tid >> 3;   // tq 0..31
        int4 v = *(const int4*)(x + (size_t)(b0 + row) * 128 + tq * 4);
        tok_t[(tq * 4 + 0) * 8 + row] = v.x;
        tok_t[(tq * 4 + 1) * 8 + row] = v.y;
        tok_t[(tq * 4 + 2) * 8 + row] = v.z;
        tok_t[(tq * 4 + 3) * 8 + row] = v.w;
    }
    if (tid < 320) ((float4*)wcls_lds)[tid] = ((const float4*)W_cls)[tid];
    if (tid < 5)   bcls_lds[tid] = b_cls[tid];
    // zero BOTH h buffers fully (rows 8-15 are read as A-rows every step)
    #pragma unroll
    for (int i = 0; i < 8; ++i) ((unsigned int*)h_lds[0])[tid + i * 512] = 0;

    // precomputed LDS byte offsets (loop-invariant; buf1 = +8192 imm)
    int aoff[8];
    #pragma unroll
    for (int kt = 0; kt < 8; ++kt)
        aoff[kt] = l15 * 512 + (((quad + 4 * kt) ^ l15) << 4);
    int woff[8];   // [nt*4 + r], rows quad*4+r (only quad<2 used)
    #pragma unroll
    for (int nt = 0; nt < 2; ++nt)
        #pragma unroll
        for (int r = 0; r < 4; ++r) {
            int row = quad * 4 + r;
            int g   = (n0 >> 3) + nt * 2 + (l15 >> 3);
            woff[nt * 4 + r] = row * 512 + ((g ^ row) << 4) + (l15 & 7) * 2;
        }

    const unsigned int colByte = (unsigned int)(n0 + l15) * 2;   // within a g_P row

    // prologue: gather xp(t=0) -> gA, xp(t=1) -> gB (valid rows only)
    unsigned int gA[8] = {0,0,0,0,0,0,0,0}, gB[8] = {0,0,0,0,0,0,0,0};
    if (rowv) {
        #pragma unroll
        for (int r = 0; r < 4; ++r) {
            const int* xr = x + (size_t)(b0 + quad * 4 + r) * 128;
            const unsigned short* p0 = g_P + (size_t)xr[0] * 256 + n0 + l15;
            const unsigned short* p1 = g_P + (size_t)xr[1] * 256 + n0 + l15;
            gA[r] = p0[0]; gA[4 + r] = p0[16];
            gB[r] = p1[0]; gB[4 + r] = p1[16];
        }
    }
    barrier_lds_only();

    char* const h0 = (char*)&h_lds[0][0];

    auto step = [&](const char* hA, char* hW, unsigned int* g, int t) {
        // consume g as MFMA C operand (xp pre-added for free)
        f32x4 acc0 = { bfbits2f(g[0]), bfbits2f(g[1]), bfbits2f(g[2]), bfbits2f(g[3]) };
        f32x4 acc1 = { bfbits2f(g[4]), bfbits2f(g[5]), bfbits2f(g[6]), bfbits2f(g[7]) };
        // refill g for t+2 (in flight across 2 barriers; counted vmcnt at use)
        if (rowv && t + 2 < 128) {
            int4 tk = *(const int4*)&tok_t[(t + 2) * 8 + quad * 4];
            const unsigned short* r0 = (const unsigned short*)((const char*)g_P + ((unsigned int)tk.x * 512 + colByte));
            const unsigned short* r1 = (const unsigned short*)((const char*)g_P + ((unsigned int)tk.y * 512 + colByte));
            const unsigned short* r2 = (const unsigned short*)((const char*)g_P + ((unsigned int)tk.z * 512 + colByte));
            const unsigned short* r3 = (const unsigned short*)((const char*)g_P + ((unsigned int)tk.w * 512 + colByte));
            g[0] = r0[0]; g[4] = r0[16];
            g[1] = r1[0]; g[5] = r1[16];
            g[2] = r2[0]; g[6] = r2[16];
            g[3] = r3[0]; g[7] = r3[16];
        }
        #pragma unroll
        for (int kt = 0; kt < 8; ++kt) {
            bf16x8 a = *(const bf16x8*)(hA + aoff[kt]);
            acc0 = __builtin_amdgcn_mfma_f32_16x16x32_bf16(a, wf[0][kt], acc0, 0, 0, 0);
            acc1 = __builtin_amdgcn_mfma_f32_16x16x32_bf16(a, wf[1][kt], acc1, 0, 0, 0);
        }
        if (rowv) {
            #pragma unroll
            for (int r = 0; r < 4; ++r) {
                *(unsigned short*)(hW + woff[r])     = f2bf_fast(fast_tanh(acc0[r]));
                *(unsigned short*)(hW + woff[4 + r]) = f2bf_fast(fast_tanh(acc1[r]));
            }
        }
    };

    #pragma unroll 1
    for (int t2 = 0; t2 < 64; ++t2) {
        step(h0,        h0 + 8192, gA, 2 * t2);      // read buf0, write buf1
        barrier_lds_only();
        step(h0 + 8192, h0,        gB, 2 * t2 + 1);  // read buf1, write buf0
        barrier_lds_only();
    }

    // final h in buf0. Classifier: 4 threads per (row,c), shuffle-reduce. 8 rows x 5 cls.
    if (tid < 160) {
        int q = tid & 3, p = tid >> 2;
        int row = p / 5, c = p - row * 5;
        float acc = 0.f;
        #pragma unroll
        for (int kk = 0; kk < 64; ++kk) {
            int k = q * 64 + kk;
            int off = row * 512 + ((((k >> 3) ^ row)) << 4) + (k & 7) * 2;
            acc += bf2f(*(const unsigned short*)(h0 + off)) * wcls_lds[c * 256 + k];
        }
        acc += __shfl_xor(acc, 1);
        acc += __shfl_xor(acc, 2);
        if (q == 0) out[(size_t)(b0 + row) * 5 + c] = acc + bcls_lds[c];
    }
}

extern "C" void kernel_launch(void* const* d_in, const int* in_sizes, int n_in,
                              void* d_out, int out_size, void* d_ws, size_t ws_size,
                              hipStream_t stream)
{
    const int*   x     = (const int*)d_in[0];
    const float* emb   = (const float*)d_in[1];
    const float* W_ih  = (const float*)d_in[2];
    const float* W_hh  = (const float*)d_in[3];
    const float* b_ih  = (const float*)d_in[4];
    const float* b_hh  = (const float*)d_in[5];
    const float* W_cls = (const float*)d_in[6];
    const float* b_cls = (const float*)d_in[7];
    float*       out   = (float*)d_out;
    (void)d_ws; (void)ws_size;

    emb_proj_kernel<<<NBLK_EMB, 256, 0, stream>>>(emb, W_ih, b_ih, b_hh);
    rnn_kernel<<<512, 512, 0, stream>>>(x, W_hh, W_cls, b_cls, out);
}

// Round 4
// 232.888 us; speedup vs baseline: 1.4303x; 1.4303x over previous
//
#include <hip/hip_runtime.h>

// emb lookup -> RNN tanh(xp_t + h @ W_hh^T) over S=128 -> 5-class head.
// B=4096, S=128, D=256, VOCAB=50000. Floats f32, x int32, out f32.
//
// Phase 0 (R10): P[v] = bf16(emb[v] @ W_ih^T + b_ih + b_hh), latency-proof.
//   R0's version spent ~95us on a 77MB/12us-roofline job: 1 block/CU, 2x
//   __syncthreads per tile = s_waitcnt vmcnt(0) drains killing prefetch AND
//   store pipelining (VALUBusy 0.36% on the R1 variant = pure stall).
//   Now: grid 512 (2 blocks/CU, ~200 VGPR, no min-waves cap — R2's
//   launch_bounds(256,2) capped VGPR at 128 < wf[4][8] alone -> spills),
//   tin double-buffered with ONE lgkm-only barrier per tile, f32 loads
//   issued 2 tiles ahead (fully-unrolled loop -> static prefetch regs),
//   C stored directly to g_P (wave covers full 64-col span -> L2 merges
//   lines; measured 1.45x write amp, fine). No vmcnt(0) in the loop.
//   Same cvt/MFMA/rounding order as R0 -> bit-identical P.
// Phase 1: EXACT R0 rnn (best measured 132us). R1 lgkm-barrier: neutral.
//   R2 4-wave: regressed (occupancy). R3 2-blocks/CU: scheduler never
//   co-resided 512-thr blocks (Occ 23%≈1 block) -> 2x serialization.
//   This structure is the local optimum; do not touch.

typedef __attribute__((ext_vector_type(8))) short bf16x8;   // 8 bf16 = 4 VGPRs
typedef __attribute__((ext_vector_type(4))) float f32x4;    // MFMA 16x16 accumulator

#define VOCAB 50000
#define NBLK_EMB 512
#define LDS_STRIDE 264   // emb kernel staging only

__device__ __align__(256) unsigned short g_P[VOCAB * 256];  // 25.6 MB projected table

static __device__ __forceinline__ float bf2f(unsigned short u) {
    union { unsigned int i; float f; } v; v.i = ((unsigned int)u) << 16; return v.f;
}
static __device__ __forceinline__ float bfbits2f(unsigned int zext_u16) {
    union { unsigned int i; float f; } v; v.i = zext_u16 << 16; return v.f;
}
static __device__ __forceinline__ unsigned short f2bf_rne(float f) {
    union { float f; unsigned int i; } v; v.f = f;
    unsigned int r = v.i + 0x7FFFu + ((v.i >> 16) & 1u);
    return (unsigned short)(r >> 16);
}
static __device__ __forceinline__ unsigned short f2bf_fast(float f) {   // round-half-up
    union { float f; unsigned int i; } v; v.f = f;
    return (unsigned short)((v.i + 0x8000u) >> 16);
}
static __device__ __forceinline__ bf16x8 cvt8(float4 a, float4 b) {
    bf16x8 r;
    r[0] = (short)f2bf_rne(a.x); r[1] = (short)f2bf_rne(a.y);
    r[2] = (short)f2bf_rne(a.z); r[3] = (short)f2bf_rne(a.w);
    r[4] = (short)f2bf_rne(b.x); r[5] = (short)f2bf_rne(b.y);
    r[6] = (short)f2bf_rne(b.z); r[7] = (short)f2bf_rne(b.w);
    return r;
}
static __device__ __forceinline__ bf16x8 load8_bf(const float* __restrict__ p) {
    return cvt8(((const float4*)p)[0], ((const float4*)p)[1]);
}
// tanh(x) = 1 - 2/(e^{2x}+1); med3 clamp keeps exp finite
static __device__ __forceinline__ float fast_tanh(float x) {
    x = __builtin_amdgcn_fmed3f(x, -8.f, 8.f);
    float e = __expf(2.f * x);
    return __builtin_fmaf(-2.f, __builtin_amdgcn_rcpf(e + 1.f), 1.f);
}
// Workgroup barrier that does NOT drain vmcnt: only LDS ops must be visible.
static __device__ __forceinline__ void barrier_lds_only() {
    asm volatile("s_waitcnt lgkmcnt(0)\n\ts_barrier" ::: "memory");
}

// ---------------- Phase 0: P = bf16(emb @ W_ih^T + (b_ih + b_hh)) ----------------
// 512 blocks x 256 thr (4 waves x 64 cols). Per block: up to 7 tiles at stride
// 512. Double-buffered tin, ONE lgkm barrier per tile. Hazard proof: iter i
// writes tin[i&1] pre-barrier, reads tin[i&1] post-barrier; a wave in iter i+1
// pre-barrier writes tin[(i+1)&1] while laggards (past barrier(i)) read
// tin[i&1] — disjoint; the buffer being overwritten was last read in iter i-1,
// before barrier(i), which every wave has passed.
__global__ __launch_bounds__(256)
void emb_proj_kernel(const float* __restrict__ emb,
                     const float* __restrict__ W_ih,
                     const float* __restrict__ b_ih,
                     const float* __restrict__ b_hh)
{
    __shared__ __align__(16) unsigned short tin[2][16 * LDS_STRIDE];
    const int tid  = threadIdx.x;
    const int lane = tid & 63;
    const int wid  = tid >> 6;
    const int n0   = wid * 64;
    const int row  = tid >> 4, seg = tid & 15;
    const int l15  = lane & 15;
    const int quad = lane >> 4;

    bf16x8 wf[4][8];
    float  bias[4];
    #pragma unroll
    for (int nt = 0; nt < 4; ++nt) {
        int n = n0 + nt * 16 + l15;
        bias[nt] = b_ih[n] + b_hh[n];
        #pragma unroll
        for (int kt = 0; kt < 8; ++kt)
            wf[nt][kt] = load8_bf(W_ih + n * 256 + quad * 8 + kt * 32);
    }

    const int b = blockIdx.x;
    float4 pf[2][4];   // static-indexed only (loop fully unrolled) — no scratch

    // prologue: issue loads for tiles b and b+512
    {
        const float4* s0 = (const float4*)(emb + ((size_t)b * 16 + row) * 256 + seg * 16);
        pf[0][0] = s0[0]; pf[0][1] = s0[1]; pf[0][2] = s0[2]; pf[0][3] = s0[3];
        int t1 = b + NBLK_EMB;
        if (t1 < 3125) {
            const float4* s1 = (const float4*)(emb + ((size_t)t1 * 16 + row) * 256 + seg * 16);
            pf[1][0] = s1[0]; pf[1][1] = s1[1]; pf[1][2] = s1[2]; pf[1][3] = s1[3];
        }
    }

    #pragma unroll
    for (int i = 0; i < 7; ++i) {
        int tile = b + i * NBLK_EMB;
        if (tile < 3125) {
            // stage tile i from prefetch regs (counted vmcnt wait, ~2 iters of slack)
            *(bf16x8*)(&tin[i & 1][row * LDS_STRIDE + seg * 16])     = cvt8(pf[i & 1][0], pf[i & 1][1]);
            *(bf16x8*)(&tin[i & 1][row * LDS_STRIDE + seg * 16 + 8]) = cvt8(pf[i & 1][2], pf[i & 1][3]);
            // issue loads for tile i+2 into the slot just consumed
            int tf = tile + 2 * NBLK_EMB;
            if (tf < 3125) {
                const float4* s = (const float4*)(emb + ((size_t)tf * 16 + row) * 256 + seg * 16);
                pf[i & 1][0] = s[0]; pf[i & 1][1] = s[1]; pf[i & 1][2] = s[2]; pf[i & 1][3] = s[3];
            }
            barrier_lds_only();   // tin[i&1] visible; prefetch & stores stay in flight

            f32x4 acc[4];
            #pragma unroll
            for (int nt = 0; nt < 4; ++nt) acc[nt] = (f32x4){0.f, 0.f, 0.f, 0.f};
            #pragma unroll
            for (int kt = 0; kt < 8; ++kt) {
                bf16x8 a = *(bf16x8*)(&tin[i & 1][l15 * LDS_STRIDE + quad * 8 + kt * 32]);
                #pragma unroll
                for (int nt = 0; nt < 4; ++nt)
                    acc[nt] = __builtin_amdgcn_mfma_f32_16x16x32_bf16(a, wf[nt][kt], acc[nt], 0, 0, 0);
            }
            // direct store: C row = tile*16 + quad*4 + r, col = n0 + nt*16 + l15.
            // Wave covers cols n0..n0+63 -> full 64B lines, L2 merges. Fire-and-forget.
            unsigned short* prow = g_P + ((size_t)tile * 16 + quad * 4) * 256 + n0;
            #pragma unroll
            for (int nt = 0; nt < 4; ++nt) {
                #pragma unroll
                for (int r = 0; r < 4; ++r)
                    prow[r * 256 + nt * 16 + l15] = f2bf_rne(acc[nt][r] + bias[nt]);
            }
        }
    }
}

// ---------------- Phase 1: recurrence + classifier (EXACT R0 best, 132us) ----------------
// h LDS layout (per 8KB buffer): element (row m, col c) at byte
//   m*512 + (((c>>3) ^ m) << 4) + (c&7)*2      (granule-XOR swizzle, conflict-free writes)
__global__ __launch_bounds__(512, 2)
void rnn_kernel(const int* __restrict__ x,
                const float* __restrict__ W_hh,
                const float* __restrict__ W_cls,
                const float* __restrict__ b_cls,
                float* __restrict__ out)
{
    __shared__ __align__(16) unsigned short h_lds[2][16 * 256];  // 2 x 8 KB
    __shared__ __align__(16) int tok_t[128 * 16];                // [t][row]
    __shared__ __align__(16) float wcls_lds[5 * 256];
    __shared__ float bcls_lds[5];

    const int tid  = threadIdx.x;
    const int lane = tid & 63;
    const int wid  = tid >> 6;          // 8 waves
    const int b0   = blockIdx.x * 16;
    const int n0   = wid * 32;          // wave's 32-col slice
    const int l15  = lane & 15;
    const int quad = lane >> 4;

    // W_hh -> bf16 B-fragments, VGPR-resident
    bf16x8 wf[2][8];
    #pragma unroll
    for (int nt = 0; nt < 2; ++nt) {
        int n = n0 + nt * 16 + l15;
        #pragma unroll
        for (int kt = 0; kt < 8; ++kt)
            wf[nt][kt] = load8_bf(W_hh + n * 256 + quad * 8 + kt * 32);
    }

    // stage tokens transposed: tok_t[t*16 + row]
    {
        int row = tid & 15, tq = tid >> 4;   // tq 0..31
        int4 v = *(const int4*)(x + (size_t)(b0 + row) * 128 + tq * 4);
        tok_t[(tq * 4 + 0) * 16 + row] = v.x;
        tok_t[(tq * 4 + 1) * 16 + row] = v.y;
        tok_t[(tq * 4 + 2) * 16 + row] = v.z;
        tok_t[(tq * 4 + 3) * 16 + row] = v.w;
    }
    if (tid < 320) ((float4*)wcls_lds)[tid] = ((const float4*)W_cls)[tid];
    if (tid < 5)   bcls_lds[tid] = b_cls[tid];
    #pragma unroll
    for (int i = 0; i < 4; ++i) ((unsigned int*)h_lds[0])[tid + i * 512] = 0;

    // precomputed LDS byte offsets (loop-invariant; buf1 = +8192 imm)
    int aoff[8];
    #pragma unroll
    for (int kt = 0; kt < 8; ++kt)
        aoff[kt] = l15 * 512 + (((quad + 4 * kt) ^ l15) << 4);
    int woff[8];   // [nt*4 + r]
    #pragma unroll
    for (int nt = 0; nt < 2; ++nt)
        #pragma unroll
        for (int r = 0; r < 4; ++r) {
            int row = quad * 4 + r;
            int g   = (n0 >> 3) + nt * 2 + (l15 >> 3);
            woff[nt * 4 + r] = row * 512 + ((g ^ row) << 4) + (l15 & 7) * 2;
        }

    const unsigned int colByte = (unsigned int)(n0 + l15) * 2;   // within a g_P row

    // prologue: gather xp(t=0) -> gA, xp(t=1) -> gB (C-layout: row quad*4+r, col n0+nt*16+l15)
    unsigned int gA[8], gB[8];
    #pragma unroll
    for (int r = 0; r < 4; ++r) {
        const int* xr = x + (size_t)(b0 + quad * 4 + r) * 128;
        const unsigned short* p0 = g_P + (size_t)xr[0] * 256 + n0 + l15;
        const unsigned short* p1 = g_P + (size_t)xr[1] * 256 + n0 + l15;
        gA[r] = p0[0]; gA[4 + r] = p0[16];
        gB[r] = p1[0]; gB[4 + r] = p1[16];
    }
    __syncthreads();

    char* const h0 = (char*)&h_lds[0][0];

    auto step = [&](const char* hA, char* hW, unsigned int* g, int t) {
        // consume g as MFMA C operand (xp pre-added for free)
        f32x4 acc0 = { bfbits2f(g[0]), bfbits2f(g[1]), bfbits2f(g[2]), bfbits2f(g[3]) };
        f32x4 acc1 = { bfbits2f(g[4]), bfbits2f(g[5]), bfbits2f(g[6]), bfbits2f(g[7]) };
        // refill g for t+2 (in flight across 2 barriers)
        if (t + 2 < 128) {
            int4 tk = *(const int4*)&tok_t[(t + 2) * 16 + quad * 4];
            const unsigned short* r0 = (const unsigned short*)((const char*)g_P + ((unsigned int)tk.x * 512 + colByte));
            const unsigned short* r1 = (const unsigned short*)((const char*)g_P + ((unsigned int)tk.y * 512 + colByte));
            const unsigned short* r2 = (const unsigned short*)((const char*)g_P + ((unsigned int)tk.z * 512 + colByte));
            const unsigned short* r3 = (const unsigned short*)((const char*)g_P + ((unsigned int)tk.w * 512 + colByte));
            g[0] = r0[0]; g[4] = r0[16];
            g[1] = r1[0]; g[5] = r1[16];
            g[2] = r2[0]; g[6] = r2[16];
            g[3] = r3[0]; g[7] = r3[16];
        }
        #pragma unroll
        for (int kt = 0; kt < 8; ++kt) {
            bf16x8 a = *(const bf16x8*)(hA + aoff[kt]);
            acc0 = __builtin_amdgcn_mfma_f32_16x16x32_bf16(a, wf[0][kt], acc0, 0, 0, 0);
            acc1 = __builtin_amdgcn_mfma_f32_16x16x32_bf16(a, wf[1][kt], acc1, 0, 0, 0);
        }
        #pragma unroll
        for (int r = 0; r < 4; ++r) {
            *(unsigned short*)(hW + woff[r])     = f2bf_fast(fast_tanh(acc0[r]));
            *(unsigned short*)(hW + woff[4 + r]) = f2bf_fast(fast_tanh(acc1[r]));
        }
    };

    #pragma unroll 1
    for (int t2 = 0; t2 < 64; ++t2) {
        step(h0,        h0 + 8192, gA, 2 * t2);      // read buf0, write buf1
        __syncthreads();
        step(h0 + 8192, h0,        gB, 2 * t2 + 1);  // read buf1, write buf0
        __syncthreads();
    }

    // final h in buf0. Classifier: 4 threads per (row,c), shuffle-reduce.
    if (tid < 320) {
        int q = tid & 3, p = tid >> 2;
        int row = p / 5, c = p - row * 5;
        float acc = 0.f;
        #pragma unroll
        for (int kk = 0; kk < 64; ++kk) {
            int k = q * 64 + kk;
            int off = row * 512 + ((((k >> 3) ^ row)) << 4) + (k & 7) * 2;
            acc += bf2f(*(const unsigned short*)(h0 + off)) * wcls_lds[c * 256 + k];
        }
        acc += __shfl_xor(acc, 1);
        acc += __shfl_xor(acc, 2);
        if (q == 0) out[(size_t)(b0 + row) * 5 + c] = acc + bcls_lds[c];
    }
}

extern "C" void kernel_launch(void* const* d_in, const int* in_sizes, int n_in,
                              void* d_out, int out_size, void* d_ws, size_t ws_size,
                              hipStream_t stream)
{
    const int*   x     = (const int*)d_in[0];
    const float* emb   = (const float*)d_in[1];
    const float* W_ih  = (const float*)d_in[2];
    const float* W_hh  = (const float*)d_in[3];
    const float* b_ih  = (const float*)d_in[4];
    const float* b_hh  = (const float*)d_in[5];
    const float* W_cls = (const float*)d_in[6];
    const float* b_cls = (const float*)d_in[7];
    float*       out   = (float*)d_out;
    (void)d_ws; (void)ws_size;

    emb_proj_kernel<<<NBLK_EMB, 256, 0, stream>>>(emb, W_ih, b_ih, b_hh);
    rnn_kernel<<<256, 512, 0, stream>>>(x, W_hh, W_cls, b_cls, out);
}